// Round 7
// baseline (387.580 us; speedup 1.0000x reference)
//
#include <hip/hip_runtime.h>

// BusStopPredictor: 2x SAGEConv(mean) + BN(eval) + ReLU, then Linear(64->1).
// N=50000 nodes, E=800000 edges, 32 -> 64 -> 64 -> 1.
//
// Round 1: dst-sorted CSR + per-node gather (no float atomics): 1251 -> 374us.
// Round 2: node GEMMs 16-lanes-per-node: 374 -> 337us.
// Round 4: LDS weights + 4 nodes/thread; node1 full-unroll spilled (VGPR=256,
//          104MB scratch): 337 -> 371us.
// Round 5: node1 unroll capped at 4 + gathers split 2 edge-slots/node:
//          371 -> 284us. Top dispatch now k_fill (54us, WRITE_SIZE 52MB vs
//          3.2MB logical csr -> cross-XCD partial-line write-back thrash).
// Round 6: k_fill -> XCD-partitioned fill. Each block reads HW_REG_XCC_ID and
//          writes only edges whose dst is in its XCD's node range (csr
//          dst-sorted => contiguous segment per range => single-XCD full-line
//          write-back). Work-stealing over per-range chunk cursors keeps
//          correctness independent of dispatch (G16). Costs 8x sequential
//          re-read of edge list (~51MB, L3-served) to kill ~49MB of partial
//          HBM write-back.

constexpr int NN = 50000;
constexpr int NE = 800000;
constexpr int NB = (NN + 255) / 256;    // 196 blocks for node-sized scans
constexpr int NBLK = (NN + 63) / 64;    // 782 blocks for 64-nodes-per-block
constexpr float BN_EPS = 1e-5f;

constexpr int FILL_CHUNK = 2000;                 // edges per claim
constexpr int FILL_NCHUNK = NE / FILL_CHUNK;     // 400
constexpr int RANGE_N = NN / 8;                  // 6250 nodes per XCD range

// ---------------- degree histogram (int) ----------------
__global__ __launch_bounds__(256) void k_deg(const int* __restrict__ ei,
                                             int* __restrict__ deg_i) {
    int e = blockIdx.x * 256 + threadIdx.x;
    if (e < NE) atomicAdd(&deg_i[ei[NE + e]], 1);
}

// ---------------- exclusive scan of deg -> base (3 kernels) ----------------
__global__ __launch_bounds__(256) void k_scan1(const int* __restrict__ deg_i,
                                               int* __restrict__ base,
                                               int* __restrict__ bsums) {
    __shared__ int s[256];
    int tid = threadIdx.x;
    int i = blockIdx.x * 256 + tid;
    int v = (i < NN) ? deg_i[i] : 0;
    s[tid] = v;
    __syncthreads();
#pragma unroll
    for (int off = 1; off < 256; off <<= 1) {
        int t = (tid >= off) ? s[tid - off] : 0;
        __syncthreads();
        s[tid] += t;
        __syncthreads();
    }
    if (i < NN) base[i] = s[tid] - v;  // exclusive within block
    if (tid == 255) bsums[blockIdx.x] = s[255];
}

__global__ __launch_bounds__(256) void k_scan2(int* __restrict__ bsums) {
    __shared__ int s[256];
    int tid = threadIdx.x;
    int v = (tid < NB) ? bsums[tid] : 0;
    s[tid] = v;
    __syncthreads();
#pragma unroll
    for (int off = 1; off < 256; off <<= 1) {
        int t = (tid >= off) ? s[tid - off] : 0;
        __syncthreads();
        s[tid] += t;
        __syncthreads();
    }
    if (tid < NB) bsums[tid] = s[tid] - v;  // exclusive block offsets
}

__global__ __launch_bounds__(256) void k_scan3(int* __restrict__ base,
                                               const int* __restrict__ bsums) {
    int i = blockIdx.x * 256 + threadIdx.x;
    if (i < NN) base[i] += bsums[blockIdx.x];
}

// ---------------- CSR fill, XCD-partitioned ----------------
// Node ranges r=0..7: [r*6250, (r+1)*6250). A block on XCD x serves range x
// first (csr segment for that range is contiguous => all its line writes come
// from one XCD => clean full-line write-back), then steals remaining ranges'
// chunks via the same exactly-once cursors (correct under any dispatch).
// After this kernel, base[n] == row_end[n].
__global__ __launch_bounds__(256) void k_fill_xcd(const int* __restrict__ ei,
                                                  int* __restrict__ base,
                                                  int* __restrict__ csr_src,
                                                  int* __restrict__ cursors) {
    int myxcd;
    asm volatile("s_getreg_b32 %0, hwreg(HW_REG_XCC_ID)" : "=s"(myxcd));
    myxcd &= 7;
    __shared__ int sc;
    for (int rr = 0; rr < 8; rr++) {
        int r = (myxcd + rr) & 7;
        int lo = r * RANGE_N, hi = lo + RANGE_N;
        while (true) {
            if (threadIdx.x == 0) sc = atomicAdd(&cursors[r], 1);
            __syncthreads();
            int c = sc;
            __syncthreads();
            if (c >= FILL_NCHUNK) break;
            int e0 = c * FILL_CHUNK;
            for (int i = threadIdx.x; i < FILL_CHUNK; i += 256) {
                int e = e0 + i;
                int s = ei[e];
                int d = ei[NE + e];
                if (d >= lo && d < hi) {
                    int pos = atomicAdd(&base[d], 1);
                    csr_src[pos] = s;
                }
            }
        }
    }
}

// ---------------- gather aggregation, 32 channels ----------------
// 16 lanes per node: 2 edge-slots x 8 channel-lanes (4 ch each).
__global__ __launch_bounds__(256) void k_gather32(const int* __restrict__ csr_src,
                                                  const int* __restrict__ base,
                                                  const int* __restrict__ deg_i,
                                                  const float* __restrict__ x,
                                                  float* __restrict__ agg) {
    int t = blockIdx.x * 256 + threadIdx.x;
    int n = t >> 4;
    if (n >= NN) return;
    int p = (t >> 3) & 1;            // edge slot 0/1
    int c4 = (t & 7) << 2;           // channel offset
    int end = base[n];
    int st = end - deg_i[n];
    float4 acc = make_float4(0.f, 0.f, 0.f, 0.f);
    for (int e = st + p; e < end; e += 2) {
        int s = csr_src[e];
        float4 v = *(const float4*)(x + (size_t)s * 32 + c4);
        acc.x += v.x; acc.y += v.y; acc.z += v.z; acc.w += v.w;
    }
    acc.x += __shfl_xor(acc.x, 8, 64);
    acc.y += __shfl_xor(acc.y, 8, 64);
    acc.z += __shfl_xor(acc.z, 8, 64);
    acc.w += __shfl_xor(acc.w, 8, 64);
    if (p == 0) *(float4*)(agg + (size_t)n * 32 + c4) = acc;
}

// ---------------- gather aggregation, 64 channels ----------------
// 32 lanes per node: 2 edge-slots x 16 channel-lanes (4 ch each).
__global__ __launch_bounds__(256) void k_gather64(const int* __restrict__ csr_src,
                                                  const int* __restrict__ base,
                                                  const int* __restrict__ deg_i,
                                                  const float* __restrict__ h,
                                                  float* __restrict__ agg) {
    int t = blockIdx.x * 256 + threadIdx.x;
    int n = t >> 5;
    if (n >= NN) return;
    int p = (t >> 4) & 1;            // edge slot 0/1
    int c4 = (t & 15) << 2;          // channel offset
    int end = base[n];
    int st = end - deg_i[n];
    float4 acc = make_float4(0.f, 0.f, 0.f, 0.f);
    for (int e = st + p; e < end; e += 2) {
        int s = csr_src[e];
        float4 v = *(const float4*)(h + (size_t)s * 64 + c4);
        acc.x += v.x; acc.y += v.y; acc.z += v.z; acc.w += v.w;
    }
    acc.x += __shfl_xor(acc.x, 16, 64);
    acc.y += __shfl_xor(acc.y, 16, 64);
    acc.z += __shfl_xor(acc.z, 16, 64);
    acc.w += __shfl_xor(acc.w, 16, 64);
    if (p == 0) *(float4*)(agg + (size_t)n * 64 + c4) = acc;
}

// ---------------- node update layer 1 ----------------
// h = relu(bn1(agg*deg_inv @ W1l + b1l + x @ W1r))
// Block = 64 nodes. W1l|W1r staged in LDS (16KB). 16 lanes per node x 4
// out-ch per lane; 4 nodes per thread (4 independent acc chains).
// unroll capped at 4: full unroll spilled (VGPR=256, 104MB scratch, r4).
__global__ __launch_bounds__(256) void k_node1(
    const float* __restrict__ x, const float* __restrict__ agg,
    const int* __restrict__ deg_i,
    const float* __restrict__ W1l, const float* __restrict__ b1l,
    const float* __restrict__ W1r,
    const float* __restrict__ g1, const float* __restrict__ bb1,
    const float* __restrict__ m1, const float* __restrict__ v1,
    float* __restrict__ h) {
    __shared__ float wlds[32 * 128];
    int tid = threadIdx.x;
    {
        const float4* l4 = (const float4*)W1l;   // 512 float4
        const float4* r4 = (const float4*)W1r;
        float4* s4 = (float4*)wlds;
#pragma unroll
        for (int i = 0; i < 2; i++) {
            int idx = tid + i * 256;
            int k = idx >> 4, c = idx & 15;
            s4[k * 32 + c] = l4[idx];
            s4[k * 32 + 16 + c] = r4[idx];
        }
    }
    __syncthreads();

    int lg = tid & 15, o4 = lg << 2;
    int nbase = blockIdx.x * 64 + (tid >> 4) * 4;
    if (nbase >= NN) return;

    float4 acc[4];
    float di[4];
    int nj[4];
#pragma unroll
    for (int j = 0; j < 4; j++) {
        acc[j] = make_float4(0.f, 0.f, 0.f, 0.f);
        nj[j] = min(nbase + j, NN - 1);   // clamp: loads stay in-bounds
        di[j] = 1.0f / fmaxf((float)deg_i[nj[j]], 1.0f);
    }

#pragma unroll 4
    for (int i4 = 0; i4 < 32; i4 += 4) {
        float4 wl[4], wr[4];
#pragma unroll
        for (int k = 0; k < 4; k++) {
            wl[k] = *(const float4*)&wlds[(i4 + k) * 128 + o4];
            wr[k] = *(const float4*)&wlds[(i4 + k) * 128 + 64 + o4];
        }
#pragma unroll
        for (int j = 0; j < 4; j++) {
            float4 a4 = *(const float4*)(agg + (size_t)nj[j] * 32 + i4);
            float4 x4 = *(const float4*)(x + (size_t)nj[j] * 32 + i4);
            float av[4] = {a4.x * di[j], a4.y * di[j], a4.z * di[j], a4.w * di[j]};
            float xv[4] = {x4.x, x4.y, x4.z, x4.w};
#pragma unroll
            for (int k = 0; k < 4; k++) {
                acc[j].x += av[k] * wl[k].x + xv[k] * wr[k].x;
                acc[j].y += av[k] * wl[k].y + xv[k] * wr[k].y;
                acc[j].z += av[k] * wl[k].z + xv[k] * wr[k].z;
                acc[j].w += av[k] * wl[k].w + xv[k] * wr[k].w;
            }
        }
    }

    float4 bl = *(const float4*)(b1l + o4);
    float4 gg = *(const float4*)(g1 + o4);
    float4 bb = *(const float4*)(bb1 + o4);
    float4 mm = *(const float4*)(m1 + o4);
    float4 vv = *(const float4*)(v1 + o4);
    float4 sc;
    sc.x = gg.x * rsqrtf(vv.x + BN_EPS);
    sc.y = gg.y * rsqrtf(vv.y + BN_EPS);
    sc.z = gg.z * rsqrtf(vv.z + BN_EPS);
    sc.w = gg.w * rsqrtf(vv.w + BN_EPS);
#pragma unroll
    for (int j = 0; j < 4; j++) {
        if (nbase + j >= NN) break;
        float4 r;
        r.x = fmaxf((acc[j].x + bl.x - mm.x) * sc.x + bb.x, 0.0f);
        r.y = fmaxf((acc[j].y + bl.y - mm.y) * sc.y + bb.y, 0.0f);
        r.z = fmaxf((acc[j].z + bl.z - mm.z) * sc.z + bb.z, 0.0f);
        r.w = fmaxf((acc[j].w + bl.w - mm.w) * sc.w + bb.w, 0.0f);
        *(float4*)(h + (size_t)(nbase + j) * 64 + o4) = r;
    }
}

// ---------------- node update layer 2 + final linear ----------------
// out = relu(bn2(agg*deg_inv @ W2l + b2l + h @ W2r)) @ Wlin + blin
// Same structure as k_node1 (LDS weights 32KB, 4 nodes/thread); final dot
// reduced across the 16-lane group.
__global__ __launch_bounds__(256) void k_node2(
    const float* __restrict__ h, const float* __restrict__ agg,
    const int* __restrict__ deg_i,
    const float* __restrict__ W2l, const float* __restrict__ b2l,
    const float* __restrict__ W2r,
    const float* __restrict__ g2, const float* __restrict__ bb2,
    const float* __restrict__ m2, const float* __restrict__ v2,
    const float* __restrict__ Wlin, const float* __restrict__ blin,
    float* __restrict__ out) {
    __shared__ float wlds[64 * 128];
    int tid = threadIdx.x;
    {
        const float4* l4 = (const float4*)W2l;   // 1024 float4
        const float4* r4 = (const float4*)W2r;
        float4* s4 = (float4*)wlds;
#pragma unroll
        for (int i = 0; i < 4; i++) {
            int idx = tid + i * 256;
            int k = idx >> 4, c = idx & 15;
            s4[k * 32 + c] = l4[idx];
            s4[k * 32 + 16 + c] = r4[idx];
        }
    }
    __syncthreads();

    int lg = tid & 15, o4 = lg << 2;
    int nbase = blockIdx.x * 64 + (tid >> 4) * 4;
    if (nbase >= NN) return;

    float4 acc[4];
    float di[4];
    int nj[4];
#pragma unroll
    for (int j = 0; j < 4; j++) {
        acc[j] = make_float4(0.f, 0.f, 0.f, 0.f);
        nj[j] = min(nbase + j, NN - 1);
        di[j] = 1.0f / fmaxf((float)deg_i[nj[j]], 1.0f);
    }

#pragma unroll 4
    for (int i4 = 0; i4 < 64; i4 += 4) {
        float4 wl[4], wr[4];
#pragma unroll
        for (int k = 0; k < 4; k++) {
            wl[k] = *(const float4*)&wlds[(i4 + k) * 128 + o4];
            wr[k] = *(const float4*)&wlds[(i4 + k) * 128 + 64 + o4];
        }
#pragma unroll
        for (int j = 0; j < 4; j++) {
            float4 a4 = *(const float4*)(agg + (size_t)nj[j] * 64 + i4);
            float4 h4 = *(const float4*)(h + (size_t)nj[j] * 64 + i4);
            float av[4] = {a4.x * di[j], a4.y * di[j], a4.z * di[j], a4.w * di[j]};
            float hv[4] = {h4.x, h4.y, h4.z, h4.w};
#pragma unroll
            for (int k = 0; k < 4; k++) {
                acc[j].x += av[k] * wl[k].x + hv[k] * wr[k].x;
                acc[j].y += av[k] * wl[k].y + hv[k] * wr[k].y;
                acc[j].z += av[k] * wl[k].z + hv[k] * wr[k].z;
                acc[j].w += av[k] * wl[k].w + hv[k] * wr[k].w;
            }
        }
    }

    float4 bl = *(const float4*)(b2l + o4);
    float4 gg = *(const float4*)(g2 + o4);
    float4 bb = *(const float4*)(bb2 + o4);
    float4 mm = *(const float4*)(m2 + o4);
    float4 vv = *(const float4*)(v2 + o4);
    float4 wo = *(const float4*)(Wlin + o4);
    float blin0 = blin[0];
    float4 sc;
    sc.x = gg.x * rsqrtf(vv.x + BN_EPS);
    sc.y = gg.y * rsqrtf(vv.y + BN_EPS);
    sc.z = gg.z * rsqrtf(vv.z + BN_EPS);
    sc.w = gg.w * rsqrtf(vv.w + BN_EPS);
#pragma unroll
    for (int j = 0; j < 4; j++) {
        float vx = fmaxf((acc[j].x + bl.x - mm.x) * sc.x + bb.x, 0.0f);
        float vy = fmaxf((acc[j].y + bl.y - mm.y) * sc.y + bb.y, 0.0f);
        float vz = fmaxf((acc[j].z + bl.z - mm.z) * sc.z + bb.z, 0.0f);
        float vw = fmaxf((acc[j].w + bl.w - mm.w) * sc.w + bb.w, 0.0f);
        float part = vx * wo.x + vy * wo.y + vz * wo.z + vw * wo.w;
#pragma unroll
        for (int m = 1; m < 16; m <<= 1) part += __shfl_xor(part, m, 64);
        if (lg == 0 && nbase + j < NN) out[nbase + j] = part + blin0;
    }
}

extern "C" void kernel_launch(void* const* d_in, const int* in_sizes, int n_in,
                              void* d_out, int out_size, void* d_ws, size_t ws_size,
                              hipStream_t stream) {
    const float* x    = (const float*)d_in[0];
    const int*   ei   = (const int*)d_in[1];
    const float* W1l  = (const float*)d_in[2];
    const float* b1l  = (const float*)d_in[3];
    const float* W1r  = (const float*)d_in[4];
    const float* g1   = (const float*)d_in[5];
    const float* bb1  = (const float*)d_in[6];
    const float* m1   = (const float*)d_in[7];
    const float* v1   = (const float*)d_in[8];
    const float* W2l  = (const float*)d_in[9];
    const float* b2l  = (const float*)d_in[10];
    const float* W2r  = (const float*)d_in[11];
    const float* g2   = (const float*)d_in[12];
    const float* bb2  = (const float*)d_in[13];
    const float* m2   = (const float*)d_in[14];
    const float* v2   = (const float*)d_in[15];
    const float* Wlin = (const float*)d_in[16];
    const float* blin = (const float*)d_in[17];
    float* out = (float*)d_out;

    // ws layout:
    //   deg_i    int[N]      degree per dst node
    //   cursors  int[8]      per-range chunk cursors for k_fill_xcd
    //   base     int[N]      exclusive scan of deg (becomes row_end after fill)
    //   bsums    int[256]    scan block sums
    //   csr      int[E]      src indices sorted by dst
    //   agg      float[64N]  aggregation buffer (reused both layers)
    //   h        float[64N]  layer-1 output
    int* deg_i   = (int*)d_ws;
    int* cursors = deg_i + NN;
    int* base    = cursors + 8;
    int* bsums   = base + NN;
    int* csr     = bsums + 256;
    float* agg   = (float*)(csr + NE);
    float* h     = agg + (size_t)64 * NN;

    // zero deg + cursors in one memset; everything else fully overwritten
    hipMemsetAsync(deg_i, 0, (size_t)(NN + 8) * sizeof(int), stream);

    k_deg<<<(NE + 255) / 256, 256, 0, stream>>>(ei, deg_i);
    k_scan1<<<NB, 256, 0, stream>>>(deg_i, base, bsums);
    k_scan2<<<1, 256, 0, stream>>>(bsums);
    k_scan3<<<NB, 256, 0, stream>>>(base, bsums);
    k_fill_xcd<<<1024, 256, 0, stream>>>(ei, base, csr, cursors);

    k_gather32<<<(NN * 16 + 255) / 256, 256, 0, stream>>>(csr, base, deg_i, x, agg);
    k_node1<<<NBLK, 256, 0, stream>>>(x, agg, deg_i, W1l, b1l, W1r,
                                      g1, bb1, m1, v1, h);
    k_gather64<<<(NN * 32 + 255) / 256, 256, 0, stream>>>(csr, base, deg_i, h, agg);
    k_node2<<<NBLK, 256, 0, stream>>>(h, agg, deg_i, W2l, b2l, W2r,
                                      g2, bb2, m2, v2, Wlin, blin, out);
}

// Round 9
// 271.979 us; speedup vs baseline: 1.4250x; 1.4250x over previous
//
#include <hip/hip_runtime.h>

// BusStopPredictor: 2x SAGEConv(mean) + BN(eval) + ReLU, then Linear(64->1).
// N=50000 nodes, E=800000 edges, 32 -> 64 -> 64 -> 1.
//
// Round 1: dst-sorted CSR + per-node gather (no float atomics): 1251 -> 374us.
// Round 2: node GEMMs 16-lanes-per-node: 374 -> 337us.
// Round 4: LDS weights + 4 nodes/thread; node1 full-unroll spilled: -> 371us.
// Round 5: node1 unroll capped at 4 + gathers 2 edge-slots/node: -> 284us.
// Round 6: XCD-partitioned fill FAILED (150us vs 54: same HBM bytes, MLP
//          destroyed by chunk-claim barriers; throughput 1049 -> 383 GB/s).
// Round 7: revert to round-5 fill but with uint16 csr (src < 65536): halves
//          the scatter write footprint that binds k_fill. Gathers widened to
//          4 edge-slots/node (halve dependent-load chain, 2x TLP).
// Round 8: resubmit unchanged (round-7 bench hit GPUAcquisitionTimeout).

constexpr int NN = 50000;
constexpr int NE = 800000;
constexpr int NB = (NN + 255) / 256;    // 196 blocks for node-sized scans
constexpr int NBLK = (NN + 63) / 64;    // 782 blocks for 64-nodes-per-block
constexpr float BN_EPS = 1e-5f;

// ---------------- degree histogram (int) ----------------
__global__ __launch_bounds__(256) void k_deg(const int* __restrict__ ei,
                                             int* __restrict__ deg_i) {
    int e = blockIdx.x * 256 + threadIdx.x;
    if (e < NE) atomicAdd(&deg_i[ei[NE + e]], 1);
}

// ---------------- exclusive scan of deg -> base (3 kernels) ----------------
__global__ __launch_bounds__(256) void k_scan1(const int* __restrict__ deg_i,
                                               int* __restrict__ base,
                                               int* __restrict__ bsums) {
    __shared__ int s[256];
    int tid = threadIdx.x;
    int i = blockIdx.x * 256 + tid;
    int v = (i < NN) ? deg_i[i] : 0;
    s[tid] = v;
    __syncthreads();
#pragma unroll
    for (int off = 1; off < 256; off <<= 1) {
        int t = (tid >= off) ? s[tid - off] : 0;
        __syncthreads();
        s[tid] += t;
        __syncthreads();
    }
    if (i < NN) base[i] = s[tid] - v;  // exclusive within block
    if (tid == 255) bsums[blockIdx.x] = s[255];
}

__global__ __launch_bounds__(256) void k_scan2(int* __restrict__ bsums) {
    __shared__ int s[256];
    int tid = threadIdx.x;
    int v = (tid < NB) ? bsums[tid] : 0;
    s[tid] = v;
    __syncthreads();
#pragma unroll
    for (int off = 1; off < 256; off <<= 1) {
        int t = (tid >= off) ? s[tid - off] : 0;
        __syncthreads();
        s[tid] += t;
        __syncthreads();
    }
    if (tid < NB) bsums[tid] = s[tid] - v;  // exclusive block offsets
}

__global__ __launch_bounds__(256) void k_scan3(int* __restrict__ base,
                                               const int* __restrict__ bsums) {
    int i = blockIdx.x * 256 + threadIdx.x;
    if (i < NN) base[i] += bsums[blockIdx.x];
}

// ---------------- CSR fill: csr_src (uint16) sorted by dst ----------------
// After this kernel, base[n] == row_end[n]; row_start[n] = base[n] - deg_i[n].
__global__ __launch_bounds__(256) void k_fill(const int* __restrict__ ei,
                                              int* __restrict__ base,
                                              unsigned short* __restrict__ csr_src) {
    int e = blockIdx.x * 256 + threadIdx.x;
    if (e >= NE) return;
    int s = ei[e];
    int d = ei[NE + e];
    int pos = atomicAdd(&base[d], 1);
    csr_src[pos] = (unsigned short)s;
}

// ---------------- gather aggregation, 32 channels ----------------
// 32 lanes per node: 4 edge-slots x 8 channel-lanes (4 ch each).
// 4 independent load chains per node; partials merged via shfl_xor(8,16).
__global__ __launch_bounds__(256) void k_gather32(const unsigned short* __restrict__ csr_src,
                                                  const int* __restrict__ base,
                                                  const int* __restrict__ deg_i,
                                                  const float* __restrict__ x,
                                                  float* __restrict__ agg) {
    int t = blockIdx.x * 256 + threadIdx.x;
    int n = t >> 5;
    if (n >= NN) return;
    int p = (t >> 3) & 3;            // edge slot 0..3
    int c4 = (t & 7) << 2;           // channel offset
    int end = base[n];
    int st = end - deg_i[n];
    float4 acc = make_float4(0.f, 0.f, 0.f, 0.f);
    for (int e = st + p; e < end; e += 4) {
        int s = csr_src[e];
        float4 v = *(const float4*)(x + (size_t)s * 32 + c4);
        acc.x += v.x; acc.y += v.y; acc.z += v.z; acc.w += v.w;
    }
    acc.x += __shfl_xor(acc.x, 8, 64);
    acc.y += __shfl_xor(acc.y, 8, 64);
    acc.z += __shfl_xor(acc.z, 8, 64);
    acc.w += __shfl_xor(acc.w, 8, 64);
    acc.x += __shfl_xor(acc.x, 16, 64);
    acc.y += __shfl_xor(acc.y, 16, 64);
    acc.z += __shfl_xor(acc.z, 16, 64);
    acc.w += __shfl_xor(acc.w, 16, 64);
    if (p == 0) *(float4*)(agg + (size_t)n * 32 + c4) = acc;
}

// ---------------- gather aggregation, 64 channels ----------------
// 64 lanes (full wave) per node: 4 edge-slots x 16 channel-lanes (4 ch each).
__global__ __launch_bounds__(256) void k_gather64(const unsigned short* __restrict__ csr_src,
                                                  const int* __restrict__ base,
                                                  const int* __restrict__ deg_i,
                                                  const float* __restrict__ h,
                                                  float* __restrict__ agg) {
    int t = blockIdx.x * 256 + threadIdx.x;
    int n = t >> 6;
    if (n >= NN) return;
    int p = (t >> 4) & 3;            // edge slot 0..3
    int c4 = (t & 15) << 2;          // channel offset
    int end = base[n];
    int st = end - deg_i[n];
    float4 acc = make_float4(0.f, 0.f, 0.f, 0.f);
    for (int e = st + p; e < end; e += 4) {
        int s = csr_src[e];
        float4 v = *(const float4*)(h + (size_t)s * 64 + c4);
        acc.x += v.x; acc.y += v.y; acc.z += v.z; acc.w += v.w;
    }
    acc.x += __shfl_xor(acc.x, 16, 64);
    acc.y += __shfl_xor(acc.y, 16, 64);
    acc.z += __shfl_xor(acc.z, 16, 64);
    acc.w += __shfl_xor(acc.w, 16, 64);
    acc.x += __shfl_xor(acc.x, 32, 64);
    acc.y += __shfl_xor(acc.y, 32, 64);
    acc.z += __shfl_xor(acc.z, 32, 64);
    acc.w += __shfl_xor(acc.w, 32, 64);
    if (p == 0) *(float4*)(agg + (size_t)n * 64 + c4) = acc;
}

// ---------------- node update layer 1 ----------------
// h = relu(bn1(agg*deg_inv @ W1l + b1l + x @ W1r))
// Block = 64 nodes. W1l|W1r staged in LDS (16KB). 16 lanes per node x 4
// out-ch per lane; 4 nodes per thread (4 independent acc chains).
// unroll capped at 4: full unroll spilled (VGPR=256, 104MB scratch, r4).
__global__ __launch_bounds__(256) void k_node1(
    const float* __restrict__ x, const float* __restrict__ agg,
    const int* __restrict__ deg_i,
    const float* __restrict__ W1l, const float* __restrict__ b1l,
    const float* __restrict__ W1r,
    const float* __restrict__ g1, const float* __restrict__ bb1,
    const float* __restrict__ m1, const float* __restrict__ v1,
    float* __restrict__ h) {
    __shared__ float wlds[32 * 128];
    int tid = threadIdx.x;
    {
        const float4* l4 = (const float4*)W1l;   // 512 float4
        const float4* r4 = (const float4*)W1r;
        float4* s4 = (float4*)wlds;
#pragma unroll
        for (int i = 0; i < 2; i++) {
            int idx = tid + i * 256;
            int k = idx >> 4, c = idx & 15;
            s4[k * 32 + c] = l4[idx];
            s4[k * 32 + 16 + c] = r4[idx];
        }
    }
    __syncthreads();

    int lg = tid & 15, o4 = lg << 2;
    int nbase = blockIdx.x * 64 + (tid >> 4) * 4;
    if (nbase >= NN) return;

    float4 acc[4];
    float di[4];
    int nj[4];
#pragma unroll
    for (int j = 0; j < 4; j++) {
        acc[j] = make_float4(0.f, 0.f, 0.f, 0.f);
        nj[j] = min(nbase + j, NN - 1);   // clamp: loads stay in-bounds
        di[j] = 1.0f / fmaxf((float)deg_i[nj[j]], 1.0f);
    }

#pragma unroll 4
    for (int i4 = 0; i4 < 32; i4 += 4) {
        float4 wl[4], wr[4];
#pragma unroll
        for (int k = 0; k < 4; k++) {
            wl[k] = *(const float4*)&wlds[(i4 + k) * 128 + o4];
            wr[k] = *(const float4*)&wlds[(i4 + k) * 128 + 64 + o4];
        }
#pragma unroll
        for (int j = 0; j < 4; j++) {
            float4 a4 = *(const float4*)(agg + (size_t)nj[j] * 32 + i4);
            float4 x4 = *(const float4*)(x + (size_t)nj[j] * 32 + i4);
            float av[4] = {a4.x * di[j], a4.y * di[j], a4.z * di[j], a4.w * di[j]};
            float xv[4] = {x4.x, x4.y, x4.z, x4.w};
#pragma unroll
            for (int k = 0; k < 4; k++) {
                acc[j].x += av[k] * wl[k].x + xv[k] * wr[k].x;
                acc[j].y += av[k] * wl[k].y + xv[k] * wr[k].y;
                acc[j].z += av[k] * wl[k].z + xv[k] * wr[k].z;
                acc[j].w += av[k] * wl[k].w + xv[k] * wr[k].w;
            }
        }
    }

    float4 bl = *(const float4*)(b1l + o4);
    float4 gg = *(const float4*)(g1 + o4);
    float4 bb = *(const float4*)(bb1 + o4);
    float4 mm = *(const float4*)(m1 + o4);
    float4 vv = *(const float4*)(v1 + o4);
    float4 sc;
    sc.x = gg.x * rsqrtf(vv.x + BN_EPS);
    sc.y = gg.y * rsqrtf(vv.y + BN_EPS);
    sc.z = gg.z * rsqrtf(vv.z + BN_EPS);
    sc.w = gg.w * rsqrtf(vv.w + BN_EPS);
#pragma unroll
    for (int j = 0; j < 4; j++) {
        if (nbase + j >= NN) break;
        float4 r;
        r.x = fmaxf((acc[j].x + bl.x - mm.x) * sc.x + bb.x, 0.0f);
        r.y = fmaxf((acc[j].y + bl.y - mm.y) * sc.y + bb.y, 0.0f);
        r.z = fmaxf((acc[j].z + bl.z - mm.z) * sc.z + bb.z, 0.0f);
        r.w = fmaxf((acc[j].w + bl.w - mm.w) * sc.w + bb.w, 0.0f);
        *(float4*)(h + (size_t)(nbase + j) * 64 + o4) = r;
    }
}

// ---------------- node update layer 2 + final linear ----------------
// out = relu(bn2(agg*deg_inv @ W2l + b2l + h @ W2r)) @ Wlin + blin
// Same structure as k_node1 (LDS weights 32KB, 4 nodes/thread); final dot
// reduced across the 16-lane group.
__global__ __launch_bounds__(256) void k_node2(
    const float* __restrict__ h, const float* __restrict__ agg,
    const int* __restrict__ deg_i,
    const float* __restrict__ W2l, const float* __restrict__ b2l,
    const float* __restrict__ W2r,
    const float* __restrict__ g2, const float* __restrict__ bb2,
    const float* __restrict__ m2, const float* __restrict__ v2,
    const float* __restrict__ Wlin, const float* __restrict__ blin,
    float* __restrict__ out) {
    __shared__ float wlds[64 * 128];
    int tid = threadIdx.x;
    {
        const float4* l4 = (const float4*)W2l;   // 1024 float4
        const float4* r4 = (const float4*)W2r;
        float4* s4 = (float4*)wlds;
#pragma unroll
        for (int i = 0; i < 4; i++) {
            int idx = tid + i * 256;
            int k = idx >> 4, c = idx & 15;
            s4[k * 32 + c] = l4[idx];
            s4[k * 32 + 16 + c] = r4[idx];
        }
    }
    __syncthreads();

    int lg = tid & 15, o4 = lg << 2;
    int nbase = blockIdx.x * 64 + (tid >> 4) * 4;
    if (nbase >= NN) return;

    float4 acc[4];
    float di[4];
    int nj[4];
#pragma unroll
    for (int j = 0; j < 4; j++) {
        acc[j] = make_float4(0.f, 0.f, 0.f, 0.f);
        nj[j] = min(nbase + j, NN - 1);
        di[j] = 1.0f / fmaxf((float)deg_i[nj[j]], 1.0f);
    }

#pragma unroll 4
    for (int i4 = 0; i4 < 64; i4 += 4) {
        float4 wl[4], wr[4];
#pragma unroll
        for (int k = 0; k < 4; k++) {
            wl[k] = *(const float4*)&wlds[(i4 + k) * 128 + o4];
            wr[k] = *(const float4*)&wlds[(i4 + k) * 128 + 64 + o4];
        }
#pragma unroll
        for (int j = 0; j < 4; j++) {
            float4 a4 = *(const float4*)(agg + (size_t)nj[j] * 64 + i4);
            float4 h4 = *(const float4*)(h + (size_t)nj[j] * 64 + i4);
            float av[4] = {a4.x * di[j], a4.y * di[j], a4.z * di[j], a4.w * di[j]};
            float hv[4] = {h4.x, h4.y, h4.z, h4.w};
#pragma unroll
            for (int k = 0; k < 4; k++) {
                acc[j].x += av[k] * wl[k].x + hv[k] * wr[k].x;
                acc[j].y += av[k] * wl[k].y + hv[k] * wr[k].y;
                acc[j].z += av[k] * wl[k].z + hv[k] * wr[k].z;
                acc[j].w += av[k] * wl[k].w + hv[k] * wr[k].w;
            }
        }
    }

    float4 bl = *(const float4*)(b2l + o4);
    float4 gg = *(const float4*)(g2 + o4);
    float4 bb = *(const float4*)(bb2 + o4);
    float4 mm = *(const float4*)(m2 + o4);
    float4 vv = *(const float4*)(v2 + o4);
    float4 wo = *(const float4*)(Wlin + o4);
    float blin0 = blin[0];
    float4 sc;
    sc.x = gg.x * rsqrtf(vv.x + BN_EPS);
    sc.y = gg.y * rsqrtf(vv.y + BN_EPS);
    sc.z = gg.z * rsqrtf(vv.z + BN_EPS);
    sc.w = gg.w * rsqrtf(vv.w + BN_EPS);
#pragma unroll
    for (int j = 0; j < 4; j++) {
        float vx = fmaxf((acc[j].x + bl.x - mm.x) * sc.x + bb.x, 0.0f);
        float vy = fmaxf((acc[j].y + bl.y - mm.y) * sc.y + bb.y, 0.0f);
        float vz = fmaxf((acc[j].z + bl.z - mm.z) * sc.z + bb.z, 0.0f);
        float vw = fmaxf((acc[j].w + bl.w - mm.w) * sc.w + bb.w, 0.0f);
        float part = vx * wo.x + vy * wo.y + vz * wo.z + vw * wo.w;
#pragma unroll
        for (int m = 1; m < 16; m <<= 1) part += __shfl_xor(part, m, 64);
        if (lg == 0 && nbase + j < NN) out[nbase + j] = part + blin0;
    }
}

extern "C" void kernel_launch(void* const* d_in, const int* in_sizes, int n_in,
                              void* d_out, int out_size, void* d_ws, size_t ws_size,
                              hipStream_t stream) {
    const float* x    = (const float*)d_in[0];
    const int*   ei   = (const int*)d_in[1];
    const float* W1l  = (const float*)d_in[2];
    const float* b1l  = (const float*)d_in[3];
    const float* W1r  = (const float*)d_in[4];
    const float* g1   = (const float*)d_in[5];
    const float* bb1  = (const float*)d_in[6];
    const float* m1   = (const float*)d_in[7];
    const float* v1   = (const float*)d_in[8];
    const float* W2l  = (const float*)d_in[9];
    const float* b2l  = (const float*)d_in[10];
    const float* W2r  = (const float*)d_in[11];
    const float* g2   = (const float*)d_in[12];
    const float* bb2  = (const float*)d_in[13];
    const float* m2   = (const float*)d_in[14];
    const float* v2   = (const float*)d_in[15];
    const float* Wlin = (const float*)d_in[16];
    const float* blin = (const float*)d_in[17];
    float* out = (float*)d_out;

    // ws layout:
    //   deg_i  int[N]        degree per dst node
    //   base   int[N]        exclusive scan of deg (becomes row_end after fill)
    //   bsums  int[256]      scan block sums
    //   csr16  ushort[E]     src indices (uint16: src < 65536) sorted by dst
    //   agg    float[64N]    aggregation buffer (reused both layers)
    //   h      float[64N]    layer-1 output
    int* deg_i = (int*)d_ws;
    int* base  = deg_i + NN;
    int* bsums = base + NN;
    unsigned short* csr16 = (unsigned short*)(bsums + 256);
    float* agg = (float*)(csr16 + NE);
    float* h   = agg + (size_t)64 * NN;

    // only deg needs zeroing; everything else is fully overwritten
    hipMemsetAsync(deg_i, 0, (size_t)NN * sizeof(int), stream);

    k_deg<<<(NE + 255) / 256, 256, 0, stream>>>(ei, deg_i);
    k_scan1<<<NB, 256, 0, stream>>>(deg_i, base, bsums);
    k_scan2<<<1, 256, 0, stream>>>(bsums);
    k_scan3<<<NB, 256, 0, stream>>>(base, bsums);
    k_fill<<<(NE + 255) / 256, 256, 0, stream>>>(ei, base, csr16);

    k_gather32<<<(NN * 32 + 255) / 256, 256, 0, stream>>>(csr16, base, deg_i, x, agg);
    k_node1<<<NBLK, 256, 0, stream>>>(x, agg, deg_i, W1l, b1l, W1r,
                                      g1, bb1, m1, v1, h);
    k_gather64<<<(NN * 64 + 255) / 256, 256, 0, stream>>>(csr16, base, deg_i, h, agg);
    k_node2<<<NBLK, 256, 0, stream>>>(h, agg, deg_i, W2l, b2l, W2r,
                                      g2, bb2, m2, v2, Wlin, blin, out);
}

// Round 10
// 269.383 us; speedup vs baseline: 1.4388x; 1.0096x over previous
//
#include <hip/hip_runtime.h>

// BusStopPredictor: 2x SAGEConv(mean) + BN(eval) + ReLU, then Linear(64->1).
// N=50000 nodes, E=800000 edges, 32 -> 64 -> 64 -> 1.
//
// Round 1: dst-sorted CSR + per-node gather (no float atomics): 1251 -> 374us.
// Round 2: node GEMMs 16-lanes-per-node: 374 -> 337us.
// Round 4: LDS weights + 4 nodes/thread; node1 full-unroll spilled: -> 371us.
// Round 5: node1 unroll capped at 4 + gathers 2 edge-slots/node: -> 284us.
// Round 6: XCD-partitioned fill FAILED (150us: chunk-claim barriers killed
//          MLP; but taught: even XCD-pinned, WRITE stayed 31.5MB -> edge
//          stream thrashes L2, evicting partial csr lines).
// Round 7/9: uint16 csr + 4-slot gathers: 284 -> 272us. fill 54 -> 46us
//          (WRITE 41.5MB = 13 atomic + ~28 partial-line csr flush).
// Round 10: fill -> static (slice,range) grid: block b handles edge slice
//          b>>3 for dst-range b&7 only. Correct by construction under any
//          dispatch; blockIdx%8 ~ XCD round-robin gives single-XCD csr
//          segments as a heuristic. NT loads for the 8x edge re-read keep
//          L2 clean so csr lines fill completely before flushing.

constexpr int NN = 50000;
constexpr int NE = 800000;
constexpr int NB = (NN + 255) / 256;    // 196 blocks for node-sized scans
constexpr int NBLK = (NN + 63) / 64;    // 782 blocks for 64-nodes-per-block
constexpr float BN_EPS = 1e-5f;

constexpr int SLICE = 2048;                      // edges per slice
constexpr int NSLICE = (NE + SLICE - 1) / SLICE; // 391
constexpr int RANGE_N = (NN + 7) / 8;            // 6250 nodes per range

// ---------------- degree histogram (int) ----------------
__global__ __launch_bounds__(256) void k_deg(const int* __restrict__ ei,
                                             int* __restrict__ deg_i) {
    int e = blockIdx.x * 256 + threadIdx.x;
    if (e < NE) {
        int d = __builtin_nontemporal_load(&ei[NE + e]);
        atomicAdd(&deg_i[d], 1);
    }
}

// ---------------- exclusive scan of deg -> base (3 kernels) ----------------
__global__ __launch_bounds__(256) void k_scan1(const int* __restrict__ deg_i,
                                               int* __restrict__ base,
                                               int* __restrict__ bsums) {
    __shared__ int s[256];
    int tid = threadIdx.x;
    int i = blockIdx.x * 256 + tid;
    int v = (i < NN) ? deg_i[i] : 0;
    s[tid] = v;
    __syncthreads();
#pragma unroll
    for (int off = 1; off < 256; off <<= 1) {
        int t = (tid >= off) ? s[tid - off] : 0;
        __syncthreads();
        s[tid] += t;
        __syncthreads();
    }
    if (i < NN) base[i] = s[tid] - v;  // exclusive within block
    if (tid == 255) bsums[blockIdx.x] = s[255];
}

__global__ __launch_bounds__(256) void k_scan2(int* __restrict__ bsums) {
    __shared__ int s[256];
    int tid = threadIdx.x;
    int v = (tid < NB) ? bsums[tid] : 0;
    s[tid] = v;
    __syncthreads();
#pragma unroll
    for (int off = 1; off < 256; off <<= 1) {
        int t = (tid >= off) ? s[tid - off] : 0;
        __syncthreads();
        s[tid] += t;
        __syncthreads();
    }
    if (tid < NB) bsums[tid] = s[tid] - v;  // exclusive block offsets
}

__global__ __launch_bounds__(256) void k_scan3(int* __restrict__ base,
                                               const int* __restrict__ bsums) {
    int i = blockIdx.x * 256 + threadIdx.x;
    if (i < NN) base[i] += bsums[blockIdx.x];
}

// ---------------- CSR fill, static (slice, range) ----------------
// Block b: edge slice b>>3, dst-range b&7. Every (edge, range) pair covered
// exactly once regardless of dispatch (correct under G16); blockIdx%8 ~ XCD
// round-robin makes each 200KB csr segment single-XCD-written (heuristic).
// NT loads keep the 51MB edge re-read out of L2. After this kernel,
// base[n] == row_end[n]; row_start[n] = base[n] - deg_i[n].
__global__ __launch_bounds__(256) void k_fill_sr(const int* __restrict__ ei,
                                                 int* __restrict__ base,
                                                 unsigned short* __restrict__ csr_src) {
    int range = blockIdx.x & 7;
    int slice = blockIdx.x >> 3;
    int lo = range * RANGE_N;
    int hi = lo + RANGE_N;
    int e0 = slice * SLICE;
    int eend = min(e0 + SLICE, NE);
    for (int e = e0 + threadIdx.x; e < eend; e += 256) {
        int d = __builtin_nontemporal_load(&ei[NE + e]);
        int s = __builtin_nontemporal_load(&ei[e]);
        if (d >= lo && d < hi) {
            int pos = atomicAdd(&base[d], 1);
            csr_src[pos] = (unsigned short)s;
        }
    }
}

// ---------------- gather aggregation, 32 channels ----------------
// 32 lanes per node: 4 edge-slots x 8 channel-lanes (4 ch each).
// 4 independent load chains per node; partials merged via shfl_xor(8,16).
__global__ __launch_bounds__(256) void k_gather32(const unsigned short* __restrict__ csr_src,
                                                  const int* __restrict__ base,
                                                  const int* __restrict__ deg_i,
                                                  const float* __restrict__ x,
                                                  float* __restrict__ agg) {
    int t = blockIdx.x * 256 + threadIdx.x;
    int n = t >> 5;
    if (n >= NN) return;
    int p = (t >> 3) & 3;            // edge slot 0..3
    int c4 = (t & 7) << 2;           // channel offset
    int end = base[n];
    int st = end - deg_i[n];
    float4 acc = make_float4(0.f, 0.f, 0.f, 0.f);
    for (int e = st + p; e < end; e += 4) {
        int s = csr_src[e];
        float4 v = *(const float4*)(x + (size_t)s * 32 + c4);
        acc.x += v.x; acc.y += v.y; acc.z += v.z; acc.w += v.w;
    }
    acc.x += __shfl_xor(acc.x, 8, 64);
    acc.y += __shfl_xor(acc.y, 8, 64);
    acc.z += __shfl_xor(acc.z, 8, 64);
    acc.w += __shfl_xor(acc.w, 8, 64);
    acc.x += __shfl_xor(acc.x, 16, 64);
    acc.y += __shfl_xor(acc.y, 16, 64);
    acc.z += __shfl_xor(acc.z, 16, 64);
    acc.w += __shfl_xor(acc.w, 16, 64);
    if (p == 0) *(float4*)(agg + (size_t)n * 32 + c4) = acc;
}

// ---------------- gather aggregation, 64 channels ----------------
// 64 lanes (full wave) per node: 4 edge-slots x 16 channel-lanes (4 ch each).
__global__ __launch_bounds__(256) void k_gather64(const unsigned short* __restrict__ csr_src,
                                                  const int* __restrict__ base,
                                                  const int* __restrict__ deg_i,
                                                  const float* __restrict__ h,
                                                  float* __restrict__ agg) {
    int t = blockIdx.x * 256 + threadIdx.x;
    int n = t >> 6;
    if (n >= NN) return;
    int p = (t >> 4) & 3;            // edge slot 0..3
    int c4 = (t & 15) << 2;          // channel offset
    int end = base[n];
    int st = end - deg_i[n];
    float4 acc = make_float4(0.f, 0.f, 0.f, 0.f);
    for (int e = st + p; e < end; e += 4) {
        int s = csr_src[e];
        float4 v = *(const float4*)(h + (size_t)s * 64 + c4);
        acc.x += v.x; acc.y += v.y; acc.z += v.z; acc.w += v.w;
    }
    acc.x += __shfl_xor(acc.x, 16, 64);
    acc.y += __shfl_xor(acc.y, 16, 64);
    acc.z += __shfl_xor(acc.z, 16, 64);
    acc.w += __shfl_xor(acc.w, 16, 64);
    acc.x += __shfl_xor(acc.x, 32, 64);
    acc.y += __shfl_xor(acc.y, 32, 64);
    acc.z += __shfl_xor(acc.z, 32, 64);
    acc.w += __shfl_xor(acc.w, 32, 64);
    if (p == 0) *(float4*)(agg + (size_t)n * 64 + c4) = acc;
}

// ---------------- node update layer 1 ----------------
// h = relu(bn1(agg*deg_inv @ W1l + b1l + x @ W1r))
// Block = 64 nodes. W1l|W1r staged in LDS (16KB). 16 lanes per node x 4
// out-ch per lane; 4 nodes per thread (4 independent acc chains).
// unroll capped at 4: full unroll spilled (VGPR=256, 104MB scratch, r4).
__global__ __launch_bounds__(256) void k_node1(
    const float* __restrict__ x, const float* __restrict__ agg,
    const int* __restrict__ deg_i,
    const float* __restrict__ W1l, const float* __restrict__ b1l,
    const float* __restrict__ W1r,
    const float* __restrict__ g1, const float* __restrict__ bb1,
    const float* __restrict__ m1, const float* __restrict__ v1,
    float* __restrict__ h) {
    __shared__ float wlds[32 * 128];
    int tid = threadIdx.x;
    {
        const float4* l4 = (const float4*)W1l;   // 512 float4
        const float4* r4 = (const float4*)W1r;
        float4* s4 = (float4*)wlds;
#pragma unroll
        for (int i = 0; i < 2; i++) {
            int idx = tid + i * 256;
            int k = idx >> 4, c = idx & 15;
            s4[k * 32 + c] = l4[idx];
            s4[k * 32 + 16 + c] = r4[idx];
        }
    }
    __syncthreads();

    int lg = tid & 15, o4 = lg << 2;
    int nbase = blockIdx.x * 64 + (tid >> 4) * 4;
    if (nbase >= NN) return;

    float4 acc[4];
    float di[4];
    int nj[4];
#pragma unroll
    for (int j = 0; j < 4; j++) {
        acc[j] = make_float4(0.f, 0.f, 0.f, 0.f);
        nj[j] = min(nbase + j, NN - 1);   // clamp: loads stay in-bounds
        di[j] = 1.0f / fmaxf((float)deg_i[nj[j]], 1.0f);
    }

#pragma unroll 4
    for (int i4 = 0; i4 < 32; i4 += 4) {
        float4 wl[4], wr[4];
#pragma unroll
        for (int k = 0; k < 4; k++) {
            wl[k] = *(const float4*)&wlds[(i4 + k) * 128 + o4];
            wr[k] = *(const float4*)&wlds[(i4 + k) * 128 + 64 + o4];
        }
#pragma unroll
        for (int j = 0; j < 4; j++) {
            float4 a4 = *(const float4*)(agg + (size_t)nj[j] * 32 + i4);
            float4 x4 = *(const float4*)(x + (size_t)nj[j] * 32 + i4);
            float av[4] = {a4.x * di[j], a4.y * di[j], a4.z * di[j], a4.w * di[j]};
            float xv[4] = {x4.x, x4.y, x4.z, x4.w};
#pragma unroll
            for (int k = 0; k < 4; k++) {
                acc[j].x += av[k] * wl[k].x + xv[k] * wr[k].x;
                acc[j].y += av[k] * wl[k].y + xv[k] * wr[k].y;
                acc[j].z += av[k] * wl[k].z + xv[k] * wr[k].z;
                acc[j].w += av[k] * wl[k].w + xv[k] * wr[k].w;
            }
        }
    }

    float4 bl = *(const float4*)(b1l + o4);
    float4 gg = *(const float4*)(g1 + o4);
    float4 bb = *(const float4*)(bb1 + o4);
    float4 mm = *(const float4*)(m1 + o4);
    float4 vv = *(const float4*)(v1 + o4);
    float4 sc;
    sc.x = gg.x * rsqrtf(vv.x + BN_EPS);
    sc.y = gg.y * rsqrtf(vv.y + BN_EPS);
    sc.z = gg.z * rsqrtf(vv.z + BN_EPS);
    sc.w = gg.w * rsqrtf(vv.w + BN_EPS);
#pragma unroll
    for (int j = 0; j < 4; j++) {
        if (nbase + j >= NN) break;
        float4 r;
        r.x = fmaxf((acc[j].x + bl.x - mm.x) * sc.x + bb.x, 0.0f);
        r.y = fmaxf((acc[j].y + bl.y - mm.y) * sc.y + bb.y, 0.0f);
        r.z = fmaxf((acc[j].z + bl.z - mm.z) * sc.z + bb.z, 0.0f);
        r.w = fmaxf((acc[j].w + bl.w - mm.w) * sc.w + bb.w, 0.0f);
        *(float4*)(h + (size_t)(nbase + j) * 64 + o4) = r;
    }
}

// ---------------- node update layer 2 + final linear ----------------
// out = relu(bn2(agg*deg_inv @ W2l + b2l + h @ W2r)) @ Wlin + blin
// Same structure as k_node1 (LDS weights 32KB, 4 nodes/thread); final dot
// reduced across the 16-lane group.
__global__ __launch_bounds__(256) void k_node2(
    const float* __restrict__ h, const float* __restrict__ agg,
    const int* __restrict__ deg_i,
    const float* __restrict__ W2l, const float* __restrict__ b2l,
    const float* __restrict__ W2r,
    const float* __restrict__ g2, const float* __restrict__ bb2,
    const float* __restrict__ m2, const float* __restrict__ v2,
    const float* __restrict__ Wlin, const float* __restrict__ blin,
    float* __restrict__ out) {
    __shared__ float wlds[64 * 128];
    int tid = threadIdx.x;
    {
        const float4* l4 = (const float4*)W2l;   // 1024 float4
        const float4* r4 = (const float4*)W2r;
        float4* s4 = (float4*)wlds;
#pragma unroll
        for (int i = 0; i < 4; i++) {
            int idx = tid + i * 256;
            int k = idx >> 4, c = idx & 15;
            s4[k * 32 + c] = l4[idx];
            s4[k * 32 + 16 + c] = r4[idx];
        }
    }
    __syncthreads();

    int lg = tid & 15, o4 = lg << 2;
    int nbase = blockIdx.x * 64 + (tid >> 4) * 4;
    if (nbase >= NN) return;

    float4 acc[4];
    float di[4];
    int nj[4];
#pragma unroll
    for (int j = 0; j < 4; j++) {
        acc[j] = make_float4(0.f, 0.f, 0.f, 0.f);
        nj[j] = min(nbase + j, NN - 1);
        di[j] = 1.0f / fmaxf((float)deg_i[nj[j]], 1.0f);
    }

#pragma unroll 4
    for (int i4 = 0; i4 < 64; i4 += 4) {
        float4 wl[4], wr[4];
#pragma unroll
        for (int k = 0; k < 4; k++) {
            wl[k] = *(const float4*)&wlds[(i4 + k) * 128 + o4];
            wr[k] = *(const float4*)&wlds[(i4 + k) * 128 + 64 + o4];
        }
#pragma unroll
        for (int j = 0; j < 4; j++) {
            float4 a4 = *(const float4*)(agg + (size_t)nj[j] * 64 + i4);
            float4 h4 = *(const float4*)(h + (size_t)nj[j] * 64 + i4);
            float av[4] = {a4.x * di[j], a4.y * di[j], a4.z * di[j], a4.w * di[j]};
            float hv[4] = {h4.x, h4.y, h4.z, h4.w};
#pragma unroll
            for (int k = 0; k < 4; k++) {
                acc[j].x += av[k] * wl[k].x + hv[k] * wr[k].x;
                acc[j].y += av[k] * wl[k].y + hv[k] * wr[k].y;
                acc[j].z += av[k] * wl[k].z + hv[k] * wr[k].z;
                acc[j].w += av[k] * wl[k].w + hv[k] * wr[k].w;
            }
        }
    }

    float4 bl = *(const float4*)(b2l + o4);
    float4 gg = *(const float4*)(g2 + o4);
    float4 bb = *(const float4*)(bb2 + o4);
    float4 mm = *(const float4*)(m2 + o4);
    float4 vv = *(const float4*)(v2 + o4);
    float4 wo = *(const float4*)(Wlin + o4);
    float blin0 = blin[0];
    float4 sc;
    sc.x = gg.x * rsqrtf(vv.x + BN_EPS);
    sc.y = gg.y * rsqrtf(vv.y + BN_EPS);
    sc.z = gg.z * rsqrtf(vv.z + BN_EPS);
    sc.w = gg.w * rsqrtf(vv.w + BN_EPS);
#pragma unroll
    for (int j = 0; j < 4; j++) {
        float vx = fmaxf((acc[j].x + bl.x - mm.x) * sc.x + bb.x, 0.0f);
        float vy = fmaxf((acc[j].y + bl.y - mm.y) * sc.y + bb.y, 0.0f);
        float vz = fmaxf((acc[j].z + bl.z - mm.z) * sc.z + bb.z, 0.0f);
        float vw = fmaxf((acc[j].w + bl.w - mm.w) * sc.w + bb.w, 0.0f);
        float part = vx * wo.x + vy * wo.y + vz * wo.z + vw * wo.w;
#pragma unroll
        for (int m = 1; m < 16; m <<= 1) part += __shfl_xor(part, m, 64);
        if (lg == 0 && nbase + j < NN) out[nbase + j] = part + blin0;
    }
}

extern "C" void kernel_launch(void* const* d_in, const int* in_sizes, int n_in,
                              void* d_out, int out_size, void* d_ws, size_t ws_size,
                              hipStream_t stream) {
    const float* x    = (const float*)d_in[0];
    const int*   ei   = (const int*)d_in[1];
    const float* W1l  = (const float*)d_in[2];
    const float* b1l  = (const float*)d_in[3];
    const float* W1r  = (const float*)d_in[4];
    const float* g1   = (const float*)d_in[5];
    const float* bb1  = (const float*)d_in[6];
    const float* m1   = (const float*)d_in[7];
    const float* v1   = (const float*)d_in[8];
    const float* W2l  = (const float*)d_in[9];
    const float* b2l  = (const float*)d_in[10];
    const float* W2r  = (const float*)d_in[11];
    const float* g2   = (const float*)d_in[12];
    const float* bb2  = (const float*)d_in[13];
    const float* m2   = (const float*)d_in[14];
    const float* v2   = (const float*)d_in[15];
    const float* Wlin = (const float*)d_in[16];
    const float* blin = (const float*)d_in[17];
    float* out = (float*)d_out;

    // ws layout:
    //   deg_i  int[N]        degree per dst node
    //   base   int[N]        exclusive scan of deg (becomes row_end after fill)
    //   bsums  int[256]      scan block sums
    //   csr16  ushort[E]     src indices (uint16: src < 65536) sorted by dst
    //   agg    float[64N]    aggregation buffer (reused both layers)
    //   h      float[64N]    layer-1 output
    int* deg_i = (int*)d_ws;
    int* base  = deg_i + NN;
    int* bsums = base + NN;
    unsigned short* csr16 = (unsigned short*)(bsums + 256);
    float* agg = (float*)(csr16 + NE);
    float* h   = agg + (size_t)64 * NN;

    // only deg needs zeroing; everything else is fully overwritten
    hipMemsetAsync(deg_i, 0, (size_t)NN * sizeof(int), stream);

    k_deg<<<(NE + 255) / 256, 256, 0, stream>>>(ei, deg_i);
    k_scan1<<<NB, 256, 0, stream>>>(deg_i, base, bsums);
    k_scan2<<<1, 256, 0, stream>>>(bsums);
    k_scan3<<<NB, 256, 0, stream>>>(base, bsums);
    k_fill_sr<<<NSLICE * 8, 256, 0, stream>>>(ei, base, csr16);

    k_gather32<<<(NN * 32 + 255) / 256, 256, 0, stream>>>(csr16, base, deg_i, x, agg);
    k_node1<<<NBLK, 256, 0, stream>>>(x, agg, deg_i, W1l, b1l, W1r,
                                      g1, bb1, m1, v1, h);
    k_gather64<<<(NN * 64 + 255) / 256, 256, 0, stream>>>(csr16, base, deg_i, h, agg);
    k_node2<<<NBLK, 256, 0, stream>>>(h, agg, deg_i, W2l, b2l, W2r,
                                      g2, bb2, m2, v2, Wlin, blin, out);
}

// Round 11
// 213.988 us; speedup vs baseline: 1.8112x; 1.2589x over previous
//
#include <hip/hip_runtime.h>

// BusStopPredictor: 2x SAGEConv(mean) + BN(eval) + ReLU, then Linear(64->1).
// N=50000 nodes, E=800000 edges, 32 -> 64 -> 64 -> 1.
//
// Round 1: dst-sorted CSR + per-node gather (no float atomics): 1251 -> 374us.
// Round 2: node GEMMs 16-lanes-per-node: 374 -> 337us.
// Round 4: LDS weights + 4 nodes/thread; node1 full-unroll spilled: -> 371us.
// Round 5: node1 unroll capped at 4 + gathers 2 edge-slots/node: -> 284us.
// Round 6: XCD-partitioned fill FAILED (chunk-claim barriers killed MLP).
// Round 7/9: uint16 csr + 4-slot gathers: 284 -> 272us (fill 54 -> 46).
// Round 10: slice x range static fill + NT: 269us; fill ~43us (fallback case).
//   Lesson: ANY edge-order scatter into dst-ordered csr pays 25-40MB of
//   partial-line write-back (each 64B line fed 2B at a time by ~20 blocks).
// Round 11: two-pass LDS radix by dst. Pass A bins packed (dst<<16|src) into
//   196 x 256-node buckets (LDS ranks + 1 global claim per block-bucket).
//   Pass B: one block per bucket stages edges in LDS, LDS-counts degrees,
//   LDS-scans offsets, writes deg/base AND the csr segment -- every csr line
//   assembled by ONE block, written once. Replaces k_deg + 3 scan kernels.

constexpr int NN = 50000;
constexpr int NE = 800000;
constexpr int NBLK = (NN + 63) / 64;    // 782 blocks for 64-nodes-per-block
constexpr float BN_EPS = 1e-5f;

constexpr int NBUCK = 196;              // buckets of 256 nodes (dst>>8)
constexpr int BCAP  = 8192;             // per-bucket region capacity (avg 4082)
constexpr int APB   = 2048;             // edges per pass-A block
constexpr int NAB   = (NE + APB - 1) / APB;  // 391

// ---------------- pass A: bin edges by dst>>8 ----------------
// Packed edge (dst<<16)|src (both < 65536). Per-block LDS rank counters give
// each (block,bucket) run a contiguous slot claimed with ONE global atomic.
__global__ __launch_bounds__(256) void k_binA(const int* __restrict__ ei,
                                              int* __restrict__ cursor,
                                              unsigned int* __restrict__ region) {
    __shared__ int lcnt[NBUCK];
    __shared__ int gb[NBUCK];
    int tid = threadIdx.x;
    for (int i = tid; i < NBUCK; i += 256) lcnt[i] = 0;
    __syncthreads();
    int e0 = blockIdx.x * APB;
    unsigned int pk[8];
    int bk[8], rk[8];
#pragma unroll
    for (int i = 0; i < 8; i++) {
        int e = e0 + i * 256 + tid;
        bk[i] = -1;
        if (e < NE) {
            int s = ei[e];
            int d = ei[NE + e];
            pk[i] = ((unsigned int)d << 16) | (unsigned int)s;
            bk[i] = d >> 8;
            rk[i] = atomicAdd(&lcnt[bk[i]], 1);
        }
    }
    __syncthreads();
    if (tid < NBUCK && lcnt[tid] > 0) gb[tid] = atomicAdd(&cursor[tid], lcnt[tid]);
    __syncthreads();
#pragma unroll
    for (int i = 0; i < 8; i++) {
        if (bk[i] >= 0) region[bk[i] * BCAP + gb[bk[i]] + rk[i]] = pk[i];
    }
}

// ---------------- pass B: build csr segment per bucket ----------------
// Block b owns nodes [b*256, b*256+256). Stages its region in LDS, counts
// per-node degrees (LDS atomics), scans offsets, writes deg_i[n],
// base[n] (= row_end, gather contract) and csr16 -- all coalesced,
// single-block-owned lines.
__global__ __launch_bounds__(256) void k_binB(const int* __restrict__ cursor,
                                              const unsigned int* __restrict__ region,
                                              int* __restrict__ deg_i,
                                              int* __restrict__ base,
                                              unsigned short* __restrict__ csr16) {
    __shared__ unsigned int stg[BCAP];   // 32KB
    __shared__ int lc[256], cur[256], sctmp[256];
    int tid = threadIdx.x;
    int b = blockIdx.x;

    // exclusive scan of all bucket counts -> my csr base B0
    int cntt = (tid < NBUCK) ? cursor[tid] : 0;
    sctmp[tid] = cntt;
    __syncthreads();
    for (int off = 1; off < 256; off <<= 1) {
        int t = (tid >= off) ? sctmp[tid - off] : 0;
        __syncthreads();
        sctmp[tid] += t;
        __syncthreads();
    }
    int B0 = (b == 0) ? 0 : sctmp[b - 1];
    int mycnt = cursor[b];

    // stage bucket edges + zero degree counters
    for (int k = tid; k < mycnt; k += 256) stg[k] = region[b * BCAP + k];
    lc[tid] = 0;
    __syncthreads();

    int node0 = b << 8;
    for (int k = tid; k < mycnt; k += 256) {
        int local = (int)(stg[k] >> 16) - node0;
        atomicAdd(&lc[local], 1);
    }
    __syncthreads();

    // exclusive scan of per-node counts
    int myc = lc[tid];
    sctmp[tid] = myc;
    __syncthreads();
    for (int off = 1; off < 256; off <<= 1) {
        int t = (tid >= off) ? sctmp[tid - off] : 0;
        __syncthreads();
        sctmp[tid] += t;
        __syncthreads();
    }
    int myoff = sctmp[tid] - myc;
    cur[tid] = myoff;
    int n = node0 + tid;
    if (n < NN) {
        deg_i[n] = myc;
        base[n] = B0 + myoff + myc;   // row_end (gather contract)
    }
    __syncthreads();

    // place csr entries (scattered only within this block's 8KB segment)
    for (int k = tid; k < mycnt; k += 256) {
        unsigned int p = stg[k];
        int local = (int)(p >> 16) - node0;
        int pos = atomicAdd(&cur[local], 1);
        csr16[B0 + pos] = (unsigned short)(p & 0xffffu);
    }
}

// ---------------- gather aggregation, 32 channels ----------------
// 32 lanes per node: 4 edge-slots x 8 channel-lanes (4 ch each).
__global__ __launch_bounds__(256) void k_gather32(const unsigned short* __restrict__ csr_src,
                                                  const int* __restrict__ base,
                                                  const int* __restrict__ deg_i,
                                                  const float* __restrict__ x,
                                                  float* __restrict__ agg) {
    int t = blockIdx.x * 256 + threadIdx.x;
    int n = t >> 5;
    if (n >= NN) return;
    int p = (t >> 3) & 3;            // edge slot 0..3
    int c4 = (t & 7) << 2;           // channel offset
    int end = base[n];
    int st = end - deg_i[n];
    float4 acc = make_float4(0.f, 0.f, 0.f, 0.f);
    for (int e = st + p; e < end; e += 4) {
        int s = csr_src[e];
        float4 v = *(const float4*)(x + (size_t)s * 32 + c4);
        acc.x += v.x; acc.y += v.y; acc.z += v.z; acc.w += v.w;
    }
    acc.x += __shfl_xor(acc.x, 8, 64);
    acc.y += __shfl_xor(acc.y, 8, 64);
    acc.z += __shfl_xor(acc.z, 8, 64);
    acc.w += __shfl_xor(acc.w, 8, 64);
    acc.x += __shfl_xor(acc.x, 16, 64);
    acc.y += __shfl_xor(acc.y, 16, 64);
    acc.z += __shfl_xor(acc.z, 16, 64);
    acc.w += __shfl_xor(acc.w, 16, 64);
    if (p == 0) *(float4*)(agg + (size_t)n * 32 + c4) = acc;
}

// ---------------- gather aggregation, 64 channels ----------------
// 64 lanes (full wave) per node: 4 edge-slots x 16 channel-lanes (4 ch each).
__global__ __launch_bounds__(256) void k_gather64(const unsigned short* __restrict__ csr_src,
                                                  const int* __restrict__ base,
                                                  const int* __restrict__ deg_i,
                                                  const float* __restrict__ h,
                                                  float* __restrict__ agg) {
    int t = blockIdx.x * 256 + threadIdx.x;
    int n = t >> 6;
    if (n >= NN) return;
    int p = (t >> 4) & 3;            // edge slot 0..3
    int c4 = (t & 15) << 2;          // channel offset
    int end = base[n];
    int st = end - deg_i[n];
    float4 acc = make_float4(0.f, 0.f, 0.f, 0.f);
    for (int e = st + p; e < end; e += 4) {
        int s = csr_src[e];
        float4 v = *(const float4*)(h + (size_t)s * 64 + c4);
        acc.x += v.x; acc.y += v.y; acc.z += v.z; acc.w += v.w;
    }
    acc.x += __shfl_xor(acc.x, 16, 64);
    acc.y += __shfl_xor(acc.y, 16, 64);
    acc.z += __shfl_xor(acc.z, 16, 64);
    acc.w += __shfl_xor(acc.w, 16, 64);
    acc.x += __shfl_xor(acc.x, 32, 64);
    acc.y += __shfl_xor(acc.y, 32, 64);
    acc.z += __shfl_xor(acc.z, 32, 64);
    acc.w += __shfl_xor(acc.w, 32, 64);
    if (p == 0) *(float4*)(agg + (size_t)n * 64 + c4) = acc;
}

// ---------------- node update layer 1 ----------------
// h = relu(bn1(agg*deg_inv @ W1l + b1l + x @ W1r))
// Block = 64 nodes. W1l|W1r staged in LDS (16KB). 16 lanes per node x 4
// out-ch per lane; 4 nodes per thread. unroll capped at 4 (r4 spill lesson).
__global__ __launch_bounds__(256) void k_node1(
    const float* __restrict__ x, const float* __restrict__ agg,
    const int* __restrict__ deg_i,
    const float* __restrict__ W1l, const float* __restrict__ b1l,
    const float* __restrict__ W1r,
    const float* __restrict__ g1, const float* __restrict__ bb1,
    const float* __restrict__ m1, const float* __restrict__ v1,
    float* __restrict__ h) {
    __shared__ float wlds[32 * 128];
    int tid = threadIdx.x;
    {
        const float4* l4 = (const float4*)W1l;   // 512 float4
        const float4* r4 = (const float4*)W1r;
        float4* s4 = (float4*)wlds;
#pragma unroll
        for (int i = 0; i < 2; i++) {
            int idx = tid + i * 256;
            int k = idx >> 4, c = idx & 15;
            s4[k * 32 + c] = l4[idx];
            s4[k * 32 + 16 + c] = r4[idx];
        }
    }
    __syncthreads();

    int lg = tid & 15, o4 = lg << 2;
    int nbase = blockIdx.x * 64 + (tid >> 4) * 4;
    if (nbase >= NN) return;

    float4 acc[4];
    float di[4];
    int nj[4];
#pragma unroll
    for (int j = 0; j < 4; j++) {
        acc[j] = make_float4(0.f, 0.f, 0.f, 0.f);
        nj[j] = min(nbase + j, NN - 1);   // clamp: loads stay in-bounds
        di[j] = 1.0f / fmaxf((float)deg_i[nj[j]], 1.0f);
    }

#pragma unroll 4
    for (int i4 = 0; i4 < 32; i4 += 4) {
        float4 wl[4], wr[4];
#pragma unroll
        for (int k = 0; k < 4; k++) {
            wl[k] = *(const float4*)&wlds[(i4 + k) * 128 + o4];
            wr[k] = *(const float4*)&wlds[(i4 + k) * 128 + 64 + o4];
        }
#pragma unroll
        for (int j = 0; j < 4; j++) {
            float4 a4 = *(const float4*)(agg + (size_t)nj[j] * 32 + i4);
            float4 x4 = *(const float4*)(x + (size_t)nj[j] * 32 + i4);
            float av[4] = {a4.x * di[j], a4.y * di[j], a4.z * di[j], a4.w * di[j]};
            float xv[4] = {x4.x, x4.y, x4.z, x4.w};
#pragma unroll
            for (int k = 0; k < 4; k++) {
                acc[j].x += av[k] * wl[k].x + xv[k] * wr[k].x;
                acc[j].y += av[k] * wl[k].y + xv[k] * wr[k].y;
                acc[j].z += av[k] * wl[k].z + xv[k] * wr[k].z;
                acc[j].w += av[k] * wl[k].w + xv[k] * wr[k].w;
            }
        }
    }

    float4 bl = *(const float4*)(b1l + o4);
    float4 gg = *(const float4*)(g1 + o4);
    float4 bb = *(const float4*)(bb1 + o4);
    float4 mm = *(const float4*)(m1 + o4);
    float4 vv = *(const float4*)(v1 + o4);
    float4 sc;
    sc.x = gg.x * rsqrtf(vv.x + BN_EPS);
    sc.y = gg.y * rsqrtf(vv.y + BN_EPS);
    sc.z = gg.z * rsqrtf(vv.z + BN_EPS);
    sc.w = gg.w * rsqrtf(vv.w + BN_EPS);
#pragma unroll
    for (int j = 0; j < 4; j++) {
        if (nbase + j >= NN) break;
        float4 r;
        r.x = fmaxf((acc[j].x + bl.x - mm.x) * sc.x + bb.x, 0.0f);
        r.y = fmaxf((acc[j].y + bl.y - mm.y) * sc.y + bb.y, 0.0f);
        r.z = fmaxf((acc[j].z + bl.z - mm.z) * sc.z + bb.z, 0.0f);
        r.w = fmaxf((acc[j].w + bl.w - mm.w) * sc.w + bb.w, 0.0f);
        *(float4*)(h + (size_t)(nbase + j) * 64 + o4) = r;
    }
}

// ---------------- node update layer 2 + final linear ----------------
// out = relu(bn2(agg*deg_inv @ W2l + b2l + h @ W2r)) @ Wlin + blin
__global__ __launch_bounds__(256) void k_node2(
    const float* __restrict__ h, const float* __restrict__ agg,
    const int* __restrict__ deg_i,
    const float* __restrict__ W2l, const float* __restrict__ b2l,
    const float* __restrict__ W2r,
    const float* __restrict__ g2, const float* __restrict__ bb2,
    const float* __restrict__ m2, const float* __restrict__ v2,
    const float* __restrict__ Wlin, const float* __restrict__ blin,
    float* __restrict__ out) {
    __shared__ float wlds[64 * 128];
    int tid = threadIdx.x;
    {
        const float4* l4 = (const float4*)W2l;   // 1024 float4
        const float4* r4 = (const float4*)W2r;
        float4* s4 = (float4*)wlds;
#pragma unroll
        for (int i = 0; i < 4; i++) {
            int idx = tid + i * 256;
            int k = idx >> 4, c = idx & 15;
            s4[k * 32 + c] = l4[idx];
            s4[k * 32 + 16 + c] = r4[idx];
        }
    }
    __syncthreads();

    int lg = tid & 15, o4 = lg << 2;
    int nbase = blockIdx.x * 64 + (tid >> 4) * 4;
    if (nbase >= NN) return;

    float4 acc[4];
    float di[4];
    int nj[4];
#pragma unroll
    for (int j = 0; j < 4; j++) {
        acc[j] = make_float4(0.f, 0.f, 0.f, 0.f);
        nj[j] = min(nbase + j, NN - 1);
        di[j] = 1.0f / fmaxf((float)deg_i[nj[j]], 1.0f);
    }

#pragma unroll 4
    for (int i4 = 0; i4 < 64; i4 += 4) {
        float4 wl[4], wr[4];
#pragma unroll
        for (int k = 0; k < 4; k++) {
            wl[k] = *(const float4*)&wlds[(i4 + k) * 128 + o4];
            wr[k] = *(const float4*)&wlds[(i4 + k) * 128 + 64 + o4];
        }
#pragma unroll
        for (int j = 0; j < 4; j++) {
            float4 a4 = *(const float4*)(agg + (size_t)nj[j] * 64 + i4);
            float4 h4 = *(const float4*)(h + (size_t)nj[j] * 64 + i4);
            float av[4] = {a4.x * di[j], a4.y * di[j], a4.z * di[j], a4.w * di[j]};
            float hv[4] = {h4.x, h4.y, h4.z, h4.w};
#pragma unroll
            for (int k = 0; k < 4; k++) {
                acc[j].x += av[k] * wl[k].x + hv[k] * wr[k].x;
                acc[j].y += av[k] * wl[k].y + hv[k] * wr[k].y;
                acc[j].z += av[k] * wl[k].z + hv[k] * wr[k].z;
                acc[j].w += av[k] * wl[k].w + hv[k] * wr[k].w;
            }
        }
    }

    float4 bl = *(const float4*)(b2l + o4);
    float4 gg = *(const float4*)(g2 + o4);
    float4 bb = *(const float4*)(bb2 + o4);
    float4 mm = *(const float4*)(m2 + o4);
    float4 vv = *(const float4*)(v2 + o4);
    float4 wo = *(const float4*)(Wlin + o4);
    float blin0 = blin[0];
    float4 sc;
    sc.x = gg.x * rsqrtf(vv.x + BN_EPS);
    sc.y = gg.y * rsqrtf(vv.y + BN_EPS);
    sc.z = gg.z * rsqrtf(vv.z + BN_EPS);
    sc.w = gg.w * rsqrtf(vv.w + BN_EPS);
#pragma unroll
    for (int j = 0; j < 4; j++) {
        float vx = fmaxf((acc[j].x + bl.x - mm.x) * sc.x + bb.x, 0.0f);
        float vy = fmaxf((acc[j].y + bl.y - mm.y) * sc.y + bb.y, 0.0f);
        float vz = fmaxf((acc[j].z + bl.z - mm.z) * sc.z + bb.z, 0.0f);
        float vw = fmaxf((acc[j].w + bl.w - mm.w) * sc.w + bb.w, 0.0f);
        float part = vx * wo.x + vy * wo.y + vz * wo.z + vw * wo.w;
#pragma unroll
        for (int m = 1; m < 16; m <<= 1) part += __shfl_xor(part, m, 64);
        if (lg == 0 && nbase + j < NN) out[nbase + j] = part + blin0;
    }
}

extern "C" void kernel_launch(void* const* d_in, const int* in_sizes, int n_in,
                              void* d_out, int out_size, void* d_ws, size_t ws_size,
                              hipStream_t stream) {
    const float* x    = (const float*)d_in[0];
    const int*   ei   = (const int*)d_in[1];
    const float* W1l  = (const float*)d_in[2];
    const float* b1l  = (const float*)d_in[3];
    const float* W1r  = (const float*)d_in[4];
    const float* g1   = (const float*)d_in[5];
    const float* bb1  = (const float*)d_in[6];
    const float* m1   = (const float*)d_in[7];
    const float* v1   = (const float*)d_in[8];
    const float* W2l  = (const float*)d_in[9];
    const float* b2l  = (const float*)d_in[10];
    const float* W2r  = (const float*)d_in[11];
    const float* g2   = (const float*)d_in[12];
    const float* bb2  = (const float*)d_in[13];
    const float* m2   = (const float*)d_in[14];
    const float* v2   = (const float*)d_in[15];
    const float* Wlin = (const float*)d_in[16];
    const float* blin = (const float*)d_in[17];
    float* out = (float*)d_out;

    // ws layout:
    //   cursor  int[256]          per-bucket claim cursors (only [0,196) used)
    //   region  u32[196*8192]     binned packed edges (6.4MB)
    //   deg_i   int[N]            degree per dst node (written by pass B)
    //   base    int[N]            row_end per node (written by pass B)
    //   csr16   ushort[E]         src indices sorted by dst
    //   agg     float[64N]        aggregation buffer (reused both layers)
    //   h       float[64N]        layer-1 output
    int* cursor = (int*)d_ws;
    unsigned int* region = (unsigned int*)(cursor + 256);
    int* deg_i = (int*)(region + (size_t)NBUCK * BCAP);
    int* base  = deg_i + NN;
    unsigned short* csr16 = (unsigned short*)(base + NN);
    float* agg = (float*)(csr16 + NE);
    float* h   = agg + (size_t)64 * NN;

    // only the bucket cursors need zeroing (1KB)
    hipMemsetAsync(cursor, 0, 256 * sizeof(int), stream);

    k_binA<<<NAB, 256, 0, stream>>>(ei, cursor, region);
    k_binB<<<NBUCK, 256, 0, stream>>>(cursor, region, deg_i, base, csr16);

    k_gather32<<<(NN * 32 + 255) / 256, 256, 0, stream>>>(csr16, base, deg_i, x, agg);
    k_node1<<<NBLK, 256, 0, stream>>>(x, agg, deg_i, W1l, b1l, W1r,
                                      g1, bb1, m1, v1, h);
    k_gather64<<<(NN * 64 + 255) / 256, 256, 0, stream>>>(csr16, base, deg_i, h, agg);
    k_node2<<<NBLK, 256, 0, stream>>>(h, agg, deg_i, W2l, b2l, W2r,
                                      g2, bb2, m2, v2, Wlin, blin, out);
}